// Round 2
// baseline (356.313 us; speedup 1.0000x reference)
//
#include <hip/hip_runtime.h>
#include <math.h>

#define B_  4
#define HH  64
#define WW  64
#define CC  64
#define C8_ 8
#define NN  4096
#define LOG2E 1.44269504088896340736f

// ---------------------------------------------------------------------------
// Kernel 1: prep — per-pixel 1x1 convs: f = relu(Wf^T x), g2 = relu(Wg^T x)*log2e,
// h = relu(Wh^T x). Layouts: f,g2 [b][n][8], h [b][n][64], n = w*64 + h.
// ---------------------------------------------------------------------------
__global__ __launch_bounds__(256) void prep_kernel(
    const float* __restrict__ x,  const float* __restrict__ Wf, const float* __restrict__ bf,
    const float* __restrict__ Wg, const float* __restrict__ bg, const float* __restrict__ Wh,
    const float* __restrict__ bh, float* __restrict__ f_out, float* __restrict__ g2_out,
    float* __restrict__ h_out)
{
    __shared__ float sWh[CC*CC];   // 16 KB
    __shared__ float sWf[CC*C8_];  // 2 KB
    __shared__ float sWg[CC*C8_];  // 2 KB
    __shared__ float sbf[C8_], sbg[C8_], sbh[CC];
    const int t = threadIdx.x;

    for (int i = t; i < CC*CC/4; i += 256) ((float4*)sWh)[i] = ((const float4*)Wh)[i];
    for (int i = t; i < CC*C8_/4; i += 256) {
        ((float4*)sWf)[i] = ((const float4*)Wf)[i];
        ((float4*)sWg)[i] = ((const float4*)Wg)[i];
    }
    if (t < C8_) { sbf[t] = bf[t]; sbg[t] = bg[t]; }
    if (t < CC)  sbh[t] = bh[t];
    __syncthreads();

    const int p = blockIdx.x * 256 + t;     // p = b*N + n
    const int b = p >> 12;
    const int n = p & (NN - 1);
    const int h = n & 63, w = n >> 6;
    const float4* xr4 = (const float4*)(x + (((size_t)(b*HH + h)*WW + w) * CC));

    float fa[C8_], ga[C8_], ha[CC];
    #pragma unroll
    for (int j = 0; j < C8_; ++j) { fa[j] = sbf[j]; ga[j] = sbg[j]; }
    #pragma unroll
    for (int d = 0; d < CC; ++d) ha[d] = sbh[d];

    #pragma unroll
    for (int c4 = 0; c4 < CC/4; ++c4) {
        float4 v = xr4[c4];
        float xs[4] = {v.x, v.y, v.z, v.w};
        #pragma unroll
        for (int u = 0; u < 4; ++u) {
            const int c = c4*4 + u;
            const float xc = xs[u];
            #pragma unroll
            for (int j = 0; j < C8_; ++j) {
                fa[j] = fmaf(sWf[c*C8_ + j], xc, fa[j]);
                ga[j] = fmaf(sWg[c*C8_ + j], xc, ga[j]);
            }
            #pragma unroll
            for (int d = 0; d < CC; ++d)
                ha[d] = fmaf(sWh[c*CC + d], xc, ha[d]);
        }
    }

    float* fp = f_out  + (size_t)p * C8_;
    float* gp = g2_out + (size_t)p * C8_;
    float* hp = h_out  + (size_t)p * CC;
    #pragma unroll
    for (int j4 = 0; j4 < 2; ++j4) {
        float4 fo, go;
        fo.x = fmaxf(fa[j4*4+0], 0.f); fo.y = fmaxf(fa[j4*4+1], 0.f);
        fo.z = fmaxf(fa[j4*4+2], 0.f); fo.w = fmaxf(fa[j4*4+3], 0.f);
        go.x = fmaxf(ga[j4*4+0], 0.f) * LOG2E; go.y = fmaxf(ga[j4*4+1], 0.f) * LOG2E;
        go.z = fmaxf(ga[j4*4+2], 0.f) * LOG2E; go.w = fmaxf(ga[j4*4+3], 0.f) * LOG2E;
        ((float4*)fp)[j4] = fo;
        ((float4*)gp)[j4] = go;
    }
    #pragma unroll
    for (int d4 = 0; d4 < CC/4; ++d4) {
        float4 ho;
        ho.x = fmaxf(ha[d4*4+0], 0.f); ho.y = fmaxf(ha[d4*4+1], 0.f);
        ho.z = fmaxf(ha[d4*4+2], 0.f); ho.w = fmaxf(ha[d4*4+3], 0.f);
        ((float4*)hp)[d4] = ho;
    }
}

// ---------------------------------------------------------------------------
// Kernel 2: pass1 — per-row (k) logsumexp in exp2-domain:
// L2[b,k] = M2 + log2(sum_n exp2(g2_k . f_n - M2)),  M2 = max_n (g2_k . f_n)
// Block: 512 threads handles 64 k-rows of one batch. Lane owns (k, n-eighth).
// ---------------------------------------------------------------------------
__global__ __launch_bounds__(512) void pass1_kernel(
    const float* __restrict__ f_in, const float* __restrict__ g2_in,
    float* __restrict__ L2_out)
{
    __shared__ float sF[128*C8_];      // 4 KB tile of f
    __shared__ float pm[8][64], pz[8][64];
    const int t  = threadIdx.x;
    const int b  = blockIdx.x >> 6;
    const int k0 = (blockIdx.x & 63) << 6;
    const int kk = t & 63;
    const int q  = t >> 6;             // 0..7
    const int k  = k0 + kk;

    const float4* gp = (const float4*)(g2_in + ((size_t)b*NN + k)*C8_);
    const float4 g0 = gp[0], g1 = gp[1];
    const float4* fb = (const float4*)(f_in + (size_t)b*NN*C8_);

    float m = 0.f, z = 0.f;            // s >= 0 always (relu inputs), so m=0 is a valid floor
    for (int T = 0; T < NN/128; ++T) {
        __syncthreads();
        if (t < 256) ((float4*)sF)[t] = fb[T*256 + t];
        __syncthreads();
        const float4* sF4 = (const float4*)sF;
        #pragma unroll 4
        for (int i = 0; i < 16; ++i) {
            const int nl = q*16 + i;
            const float4 f0 = sF4[nl*2], f1 = sF4[nl*2 + 1];
            float s = g0.x*f0.x + g0.y*f0.y + g0.z*f0.z + g0.w*f0.w
                    + g1.x*f1.x + g1.y*f1.y + g1.z*f1.z + g1.w*f1.w;
            if (s > m) { z = z * exp2f(m - s) + 1.f; m = s; }
            else       { z += exp2f(s - m); }
        }
    }
    pm[q][kk] = m; pz[q][kk] = z;
    __syncthreads();
    if (t < 64) {
        float M = pm[0][t];
        #pragma unroll
        for (int qq = 1; qq < 8; ++qq) M = fmaxf(M, pm[qq][t]);
        float Z = 0.f;
        #pragma unroll
        for (int qq = 0; qq < 8; ++qq) Z += pz[qq][t] * exp2f(pm[qq][t] - M);
        L2_out[(size_t)b*NN + k0 + t] = M + log2f(Z);
    }
}

// ---------------------------------------------------------------------------
// Kernel 3: pass2 — o[c,n] = sum_k exp2(g2_k . f_n - L2[k]) * h[k,c]
// Block: 256 threads, one (b, 64-query tile, k-half). Register tile 4c x 4n.
// XCD swizzle: bi & 7 selects (b, chunk) — all 64 n-tile blocks sharing one
// 512 KB h-chunk land on the same XCD's L2 (round-robin dispatch, bi%8→XCD).
// ---------------------------------------------------------------------------
#define SWS 68   // padded row stride for sW (68*4 B, 16B-aligned, breaks bank conflicts)
__global__ __launch_bounds__(256) void pass2_kernel(
    const float* __restrict__ f_in, const float* __restrict__ g2_in,
    const float* __restrict__ h_in, const float* __restrict__ L2_in,
    float* __restrict__ opart)
{
    __shared__ float sW[64*SWS];   // 17 KB: exp weights [k][n]
    __shared__ float sH[64*CC];    // 16 KB: h tile [k][c]
    __shared__ float sG[64*C8_];   // 2 KB
    __shared__ float sF[64*C8_];   // 2 KB
    __shared__ float sL[64];
    const int t     = threadIdx.x;
    const int bi    = blockIdx.x;
    const int xcd   = bi & 7;      // -> XCD id under round-robin dispatch
    const int chunk = xcd & 1;
    const int b     = xcd >> 1;
    const int nt    = bi >> 3;     // 0..63
    const int n0t   = nt << 6;

    if (t < 128) ((float4*)sF)[t] = ((const float4*)(f_in + ((size_t)b*NN + n0t)*C8_))[t];
    __syncthreads();

    const int nw = t & 63;         // column this thread computes in W phase
    const int kq = t >> 6;
    const float4 fv0 = ((const float4*)sF)[nw*2], fv1 = ((const float4*)sF)[nw*2 + 1];

    const int cg = t >> 4;         // 0..15 -> c0 = cg*4
    const int ng = t & 15;         // 0..15 -> n0 = ng*4
    float acc[4][4] = {{0.f}};     // [ci][nj]

    const float4* hb = (const float4*)(h_in  + ((size_t)b*NN + chunk*2048)*CC);
    const float4* gb = (const float4*)(g2_in + ((size_t)b*NN + chunk*2048)*C8_);
    const float*  Lb = L2_in + (size_t)b*NN + chunk*2048;

    for (int kt = 0; kt < 32; ++kt) {
        __syncthreads();
        #pragma unroll
        for (int i = 0; i < 4; ++i)
            ((float4*)sH)[t + 256*i] = hb[kt*1024 + t + 256*i];
        if (t < 128) ((float4*)sG)[t] = gb[kt*128 + t];
        if (t < 16)  ((float4*)sL)[t] = ((const float4*)(Lb + kt*64))[t];
        __syncthreads();

        // W phase: 16 k-rows per thread, lane-uniform k -> LDS broadcast reads
        #pragma unroll
        for (int kz = 0; kz < 16; ++kz) {
            const int k = kq*16 + kz;
            const float4 q0 = ((const float4*)sG)[k*2], q1 = ((const float4*)sG)[k*2 + 1];
            float s = q0.x*fv0.x + q0.y*fv0.y + q0.z*fv0.z + q0.w*fv0.w
                    + q1.x*fv1.x + q1.y*fv1.y + q1.z*fv1.z + q1.w*fv1.w;
            sW[k*SWS + nw] = exp2f(s - sL[k]);
        }
        __syncthreads();

        // GEMM phase: acc[ci][nj] += h[k][c0+ci] * W[k][n0+nj]
        #pragma unroll 8
        for (int k = 0; k < 64; ++k) {
            const float4 hv = ((const float4*)sH)[k*16 + cg];
            const float4 wv = ((const float4*)sW)[k*(SWS/4) + ng];
            acc[0][0] = fmaf(hv.x, wv.x, acc[0][0]);
            acc[0][1] = fmaf(hv.x, wv.y, acc[0][1]);
            acc[0][2] = fmaf(hv.x, wv.z, acc[0][2]);
            acc[0][3] = fmaf(hv.x, wv.w, acc[0][3]);
            acc[1][0] = fmaf(hv.y, wv.x, acc[1][0]);
            acc[1][1] = fmaf(hv.y, wv.y, acc[1][1]);
            acc[1][2] = fmaf(hv.y, wv.z, acc[1][2]);
            acc[1][3] = fmaf(hv.y, wv.w, acc[1][3]);
            acc[2][0] = fmaf(hv.z, wv.x, acc[2][0]);
            acc[2][1] = fmaf(hv.z, wv.y, acc[2][1]);
            acc[2][2] = fmaf(hv.z, wv.z, acc[2][2]);
            acc[2][3] = fmaf(hv.z, wv.w, acc[2][3]);
            acc[3][0] = fmaf(hv.w, wv.x, acc[3][0]);
            acc[3][1] = fmaf(hv.w, wv.y, acc[3][1]);
            acc[3][2] = fmaf(hv.w, wv.z, acc[3][2]);
            acc[3][3] = fmaf(hv.w, wv.w, acc[3][3]);
        }
    }

    float* op = opart + (((size_t)chunk*B_ + b)*NN + n0t)*CC;
    #pragma unroll
    for (int j = 0; j < 4; ++j) {
        float4 v;
        v.x = acc[0][j]; v.y = acc[1][j]; v.z = acc[2][j]; v.w = acc[3][j];
        *((float4*)(op + (size_t)(ng*4 + j)*CC + cg*4)) = v;
    }
}

// ---------------------------------------------------------------------------
// Kernel 4: epilogue — y[b,h,w,c] = gamma*(o0+o1)[b, n=w*64+h, c] + x[b,h,w,c]
// ---------------------------------------------------------------------------
__global__ __launch_bounds__(256) void epi_kernel(
    const float* __restrict__ x, const float* __restrict__ opart,
    const float* __restrict__ gamma_p, float* __restrict__ y)
{
    const int idx = blockIdx.x * 256 + threadIdx.x;   // float4 index
    const float gm = gamma_p[0];
    const int c4 = idx & 15;
    const int n  = (idx >> 4) & (NN - 1);
    const int b  = idx >> 16;
    const float4 o0 = ((const float4*)opart)[((size_t)(0*B_ + b)*NN + n)*16 + c4];
    const float4 o1 = ((const float4*)opart)[((size_t)(1*B_ + b)*NN + n)*16 + c4];
    const int h = n & 63, w = n >> 6;
    const size_t xi = ((size_t)((b*HH + h)*WW + w)*CC >> 2) + c4;
    const float4 xv = ((const float4*)x)[xi];
    float4 r;
    r.x = fmaf(gm, o0.x + o1.x, xv.x);
    r.y = fmaf(gm, o0.y + o1.y, xv.y);
    r.z = fmaf(gm, o0.z + o1.z, xv.z);
    r.w = fmaf(gm, o0.w + o1.w, xv.w);
    ((float4*)y)[xi] = r;
}

// ---------------------------------------------------------------------------
extern "C" void kernel_launch(void* const* d_in, const int* in_sizes, int n_in,
                              void* d_out, int out_size, void* d_ws, size_t ws_size,
                              hipStream_t stream)
{
    const float* x     = (const float*)d_in[0];
    const float* Wf    = (const float*)d_in[1];
    const float* bf    = (const float*)d_in[2];
    const float* Wg    = (const float*)d_in[3];
    const float* bg    = (const float*)d_in[4];
    const float* Wh    = (const float*)d_in[5];
    const float* bh    = (const float*)d_in[6];
    const float* gamma = (const float*)d_in[7];
    float* out = (float*)d_out;

    float* f_buf  = (float*)d_ws;                          // B*N*8
    float* g2_buf = f_buf  + (size_t)B_*NN*C8_;            // B*N*8
    float* h_buf  = g2_buf + (size_t)B_*NN*C8_;            // B*N*64
    float* L2_buf = h_buf  + (size_t)B_*NN*CC;             // B*N
    float* opart  = L2_buf + (size_t)B_*NN;                // 2*B*N*64
    // total: 13.1 MB of d_ws

    prep_kernel<<<B_*NN/256, 256, 0, stream>>>(x, Wf, bf, Wg, bg, Wh, bh,
                                               f_buf, g2_buf, h_buf);
    pass1_kernel<<<B_*64, 512, 0, stream>>>(f_buf, g2_buf, L2_buf);
    pass2_kernel<<<512, 256, 0, stream>>>(f_buf, g2_buf, h_buf, L2_buf, opart);
    epi_kernel<<<(B_*NN*CC/4)/256, 256, 0, stream>>>(x, opart, gamma, out);
}

// Round 4
// 207.390 us; speedup vs baseline: 1.7181x; 1.7181x over previous
//
#include <hip/hip_runtime.h>
#include <math.h>

#define B_  4
#define HH  64
#define WW  64
#define CC  64
#define C8_ 8
#define NN  4096
#define BN  (B_*NN)
#define NS  4
#define LOG2E 1.44269504088896340736f

typedef _Float16 half8 __attribute__((ext_vector_type(8)));
typedef float f32x4 __attribute__((ext_vector_type(4)));

// XOR swizzle: row stride 128B; spread the 8 16B-slots of a row by row&7.
#define SWZ(row, kbyte) (((((row) << 7) + (kbyte))) ^ (((row) & 7) << 4))

// ---------------------------------------------------------------------------
// Kernel 1: prep — f = relu(Wf^T x) [b][n][8], g2 = relu(Wg^T x)*log2e [b][n][8],
// h = relu(Wh^T x) stored C-MAJOR: h[b][c][n]  (k-contiguous for pass2 staging)
// ---------------------------------------------------------------------------
__global__ __launch_bounds__(256) void prep_kernel(
    const float* __restrict__ x,  const float* __restrict__ Wf, const float* __restrict__ bf,
    const float* __restrict__ Wg, const float* __restrict__ bg, const float* __restrict__ Wh,
    const float* __restrict__ bh, float* __restrict__ f_out, float* __restrict__ g2_out,
    float* __restrict__ h_out)
{
    __shared__ float sWh[CC*CC];
    __shared__ float sWf[CC*C8_];
    __shared__ float sWg[CC*C8_];
    __shared__ float sbf[C8_], sbg[C8_], sbh[CC];
    const int t = threadIdx.x;

    for (int i = t; i < CC*CC/4; i += 256) ((float4*)sWh)[i] = ((const float4*)Wh)[i];
    for (int i = t; i < CC*C8_/4; i += 256) {
        ((float4*)sWf)[i] = ((const float4*)Wf)[i];
        ((float4*)sWg)[i] = ((const float4*)Wg)[i];
    }
    if (t < C8_) { sbf[t] = bf[t]; sbg[t] = bg[t]; }
    if (t < CC)  sbh[t] = bh[t];
    __syncthreads();

    const int p = blockIdx.x * 256 + t;     // p = b*N + n
    const int b = p >> 12;
    const int n = p & (NN - 1);
    const int h = n & 63, w = n >> 6;
    const float4* xr4 = (const float4*)(x + (((size_t)(b*HH + h)*WW + w) * CC));

    float fa[C8_], ga[C8_], ha[CC];
    #pragma unroll
    for (int j = 0; j < C8_; ++j) { fa[j] = sbf[j]; ga[j] = sbg[j]; }
    #pragma unroll
    for (int d = 0; d < CC; ++d) ha[d] = sbh[d];

    #pragma unroll
    for (int c4 = 0; c4 < CC/4; ++c4) {
        float4 v = xr4[c4];
        float xs[4] = {v.x, v.y, v.z, v.w};
        #pragma unroll
        for (int u = 0; u < 4; ++u) {
            const int c = c4*4 + u;
            const float xc = xs[u];
            #pragma unroll
            for (int j = 0; j < C8_; ++j) {
                fa[j] = fmaf(sWf[c*C8_ + j], xc, fa[j]);
                ga[j] = fmaf(sWg[c*C8_ + j], xc, ga[j]);
            }
            #pragma unroll
            for (int d = 0; d < CC; ++d)
                ha[d] = fmaf(sWh[c*CC + d], xc, ha[d]);
        }
    }

    float* fp = f_out  + (size_t)p * C8_;
    float* gp = g2_out + (size_t)p * C8_;
    #pragma unroll
    for (int j4 = 0; j4 < 2; ++j4) {
        float4 fo, go;
        fo.x = fmaxf(fa[j4*4+0], 0.f); fo.y = fmaxf(fa[j4*4+1], 0.f);
        fo.z = fmaxf(fa[j4*4+2], 0.f); fo.w = fmaxf(fa[j4*4+3], 0.f);
        go.x = fmaxf(ga[j4*4+0], 0.f) * LOG2E; go.y = fmaxf(ga[j4*4+1], 0.f) * LOG2E;
        go.z = fmaxf(ga[j4*4+2], 0.f) * LOG2E; go.w = fmaxf(ga[j4*4+3], 0.f) * LOG2E;
        ((float4*)fp)[j4] = fo;
        ((float4*)gp)[j4] = go;
    }
    // h c-major: coalesced per-c stores (lane n consecutive)
    #pragma unroll
    for (int d = 0; d < CC; ++d)
        h_out[((size_t)(b*CC + d))*NN + n] = fmaxf(ha[d], 0.f);
}

// ---------------------------------------------------------------------------
// Kernel 2: pass1 — partial row-logsumexp over an n-quarter (NS=4 splits).
// Block handles 64 k-rows × 1024 n. Writes partial (M, Z) per row.
// ---------------------------------------------------------------------------
__global__ __launch_bounds__(512) void pass1_kernel(
    const float* __restrict__ f_in, const float* __restrict__ g2_in,
    float* __restrict__ pm_out, float* __restrict__ pz_out)
{
    __shared__ float sF[128*C8_];
    __shared__ float pm[8][64], pz[8][64];
    const int t  = threadIdx.x;
    const int bi = blockIdx.x;
    const int ktile = bi & 63;
    const int b  = (bi >> 6) & 3;
    const int ns = bi >> 8;
    const int k0 = ktile << 6;
    const int kk = t & 63;
    const int q  = t >> 6;
    const int k  = k0 + kk;

    const float4* gp = (const float4*)(g2_in + ((size_t)b*NN + k)*C8_);
    const float4 g0 = gp[0], g1 = gp[1];
    const float4* fb = ((const float4*)f_in) + (size_t)b*8192 + ns*2048;

    float m = 0.f, z = 0.f;            // s >= 0 (relu inputs), m=0 valid floor
    for (int T = 0; T < 8; ++T) {
        __syncthreads();
        if (t < 256) ((float4*)sF)[t] = fb[T*256 + t];
        __syncthreads();
        const float4* sF4 = (const float4*)sF;
        #pragma unroll 4
        for (int i = 0; i < 16; ++i) {
            const int nl = q*16 + i;
            const float4 f0 = sF4[nl*2], f1 = sF4[nl*2 + 1];
            float s = g0.x*f0.x + g0.y*f0.y + g0.z*f0.z + g0.w*f0.w
                    + g1.x*f1.x + g1.y*f1.y + g1.z*f1.z + g1.w*f1.w;
            if (s > m) { z = z * exp2f(m - s) + 1.f; m = s; }
            else       { z += exp2f(s - m); }
        }
    }
    pm[q][kk] = m; pz[q][kk] = z;
    __syncthreads();
    if (t < 64) {
        float M = pm[0][t];
        #pragma unroll
        for (int qq = 1; qq < 8; ++qq) M = fmaxf(M, pm[qq][t]);
        float Z = 0.f;
        #pragma unroll
        for (int qq = 0; qq < 8; ++qq) Z += pz[qq][t] * exp2f(pm[qq][t] - M);
        pm_out[(size_t)ns*BN + b*NN + k0 + t] = M;
        pz_out[(size_t)ns*BN + b*NN + k0 + t] = Z;
    }
}

// ---------------------------------------------------------------------------
// Kernel 2b: combine NS partials -> L2[b,k] = M + log2(Z)
// ---------------------------------------------------------------------------
__global__ __launch_bounds__(256) void lse_combine_kernel(
    const float* __restrict__ pm, const float* __restrict__ pz,
    float* __restrict__ L2_out)
{
    const int r = blockIdx.x * 256 + threadIdx.x;   // < BN
    float M = pm[r];
    #pragma unroll
    for (int ns = 1; ns < NS; ++ns) M = fmaxf(M, pm[(size_t)ns*BN + r]);
    float Z = 0.f;
    #pragma unroll
    for (int ns = 0; ns < NS; ++ns)
        Z += pz[(size_t)ns*BN + r] * exp2f(pm[(size_t)ns*BN + r] - M);
    L2_out[r] = M + log2f(Z);
}

// ---------------------------------------------------------------------------
// Kernel 3: pass2 — o[n][c] = sum_k w[k,n] * h[k,c],  w = exp2(g2_k.f_n - L2[k])
// MFMA f16 hi/lo 3-way split (fp32-accurate). Block: 256 thr, 64c x 128n tile,
// 4 waves = 2 n-pos x 2 k-halves; K-tile 64. LDS f16 [row][k] XOR-swizzled.
// Correctness of the f16 path needs only: A and B fragments share the same
// (lane-group, elem)->k mapping; D mapping col=lane&15,row=(lane>>4)*4+reg.
// ---------------------------------------------------------------------------
#define OFF_SWH 0
#define OFF_SWL 16384
#define OFF_SHH 32768
#define OFF_SHL 40960
#define OFF_SG  49152
#define OFF_SL  51200
#define LDS_SZ  51456

__global__ __launch_bounds__(256, 3) void pass2_kernel(
    const float* __restrict__ f_in, const float* __restrict__ g2_in,
    const float* __restrict__ h_in, const float* __restrict__ L2_in,
    float* __restrict__ opart, int ksplit)
{
    __shared__ __align__(16) unsigned char lds[LDS_SZ];

    const int t     = threadIdx.x;
    const int bi    = blockIdx.x;
    const int nt    = bi & 31;
    const int b     = (bi >> 5) & 3;
    const int chunk = bi >> 7;
    const int n0    = nt << 7;
    const int kchunk = NN / ksplit;
    const int kbase0 = chunk * kchunk;
    const int ktiles = kchunk >> 6;

    // roles
    const int lane = t & 63, wid = t >> 6;
    const int wn = wid & 1, kh = wid >> 1;       // GEMM: n-position, k-half
    const int nw = t & 127, kh2 = t >> 7;        // W-phase: n-column, k-half
    const int sc = t >> 2,  skq = t & 3;         // h-stage: c-row, k-quarter

    // f for W phase (column n0+nw), in registers
    const float4* fp4 = (const float4*)(f_in + ((size_t)b*NN + n0 + nw)*C8_);
    const float4 fA = fp4[0], fB = fp4[1];

    f32x4 acc[4][4] = {};

    for (int kt = 0; kt < ktiles; ++kt) {
        const int kb = kbase0 + (kt << 6);
        __syncthreads();   // prev GEMM done reading sWT/sH; prev W done with sG/sL
        // ---- phase A: stage sG, sL, h(hi/lo) ----
        if (t < 128) ((float4*)(lds + OFF_SG))[t] =
            ((const float4*)(g2_in + ((size_t)b*NN + kb)*C8_))[t];
        if (t < 16) ((float4*)(lds + OFF_SL))[t] =
            ((const float4*)(L2_in + (size_t)b*NN + kb))[t];
        {
            const float* hr = h_in + ((size_t)(b*CC + sc))*NN + kb + skq*16;
            float hv[16];
            #pragma unroll
            for (int j = 0; j < 4; ++j) {
                float4 v = ((const float4*)hr)[j];
                hv[j*4+0] = v.x; hv[j*4+1] = v.y; hv[j*4+2] = v.z; hv[j*4+3] = v.w;
            }
            #pragma unroll
            for (int half = 0; half < 2; ++half) {
                union { _Float16 h[8]; uint4 u; } ph, pl;
                #pragma unroll
                for (int j = 0; j < 8; ++j) {
                    float v = hv[half*8 + j];
                    _Float16 hi = (_Float16)v;
                    ph.h[j] = hi;
                    pl.h[j] = (_Float16)(v - (float)hi);
                }
                const int kbyte = (skq*16 + half*8) * 2;
                *(uint4*)(lds + OFF_SHH + SWZ(sc, kbyte)) = ph.u;
                *(uint4*)(lds + OFF_SHL + SWZ(sc, kbyte)) = pl.u;
            }
        }
        __syncthreads();
        // ---- phase B: W-phase — w = exp2(f.g2 - L2), split hi/lo, write sWT[n][k]
        {
            const float4* sG4 = (const float4*)(lds + OFF_SG);
            const float*  sLf = (const float*)(lds + OFF_SL);
            #pragma unroll
            for (int kk8 = 0; kk8 < 4; ++kk8) {
                union { _Float16 h[8]; uint4 u; } wh, wl;
                #pragma unroll
                for (int j = 0; j < 8; ++j) {
                    const int kkk = kh2*32 + kk8*8 + j;
                    const float4 q0 = sG4[kkk*2], q1 = sG4[kkk*2+1];
                    float s = q0.x*fA.x + q0.y*fA.y + q0.z*fA.z + q0.w*fA.w
                            + q1.x*fB.x + q1.y*fB.y + q1.z*fB.z + q1.w*fB.w;
                    float wv = exp2f(s - sLf[kkk]);
                    _Float16 hi = (_Float16)wv;
                    wh.h[j] = hi;
                    wl.h[j] = (_Float16)(wv - (float)hi);
                }
                const int kbyte = (kh2*32 + kk8*8) * 2;
                *(uint4*)(lds + OFF_SWH + SWZ(nw, kbyte)) = wh.u;
                *(uint4*)(lds + OFF_SWL + SWZ(nw, kbyte)) = wl.u;
            }
        }
        __syncthreads();
        // ---- phase C: GEMM — wave (wn, kh): 64n x 64c x 32k, 48 MFMA
        {
            const int kbyteg = (kh*32 + ((lane >> 4) << 3)) << 1;
            half8 Ah[4], Al[4];
            #pragma unroll
            for (int ai = 0; ai < 4; ++ai) {
                const int n = wn*64 + ai*16 + (lane & 15);
                Ah[ai] = *(const half8*)(lds + OFF_SWH + SWZ(n, kbyteg));
                Al[ai] = *(const half8*)(lds + OFF_SWL + SWZ(n, kbyteg));
            }
            #pragma unroll
            for (int bj = 0; bj < 4; ++bj) {
                const int c = bj*16 + (lane & 15);
                const half8 Bh = *(const half8*)(lds + OFF_SHH + SWZ(c, kbyteg));
                const half8 Bl = *(const half8*)(lds + OFF_SHL + SWZ(c, kbyteg));
                #pragma unroll
                for (int ai = 0; ai < 4; ++ai) {
                    acc[ai][bj] = __builtin_amdgcn_mfma_f32_16x16x32_f16(Ah[ai], Bh, acc[ai][bj], 0, 0, 0);
                    acc[ai][bj] = __builtin_amdgcn_mfma_f32_16x16x32_f16(Ah[ai], Bl, acc[ai][bj], 0, 0, 0);
                    acc[ai][bj] = __builtin_amdgcn_mfma_f32_16x16x32_f16(Al[ai], Bh, acc[ai][bj], 0, 0, 0);
                }
            }
        }
    }

    // ---- merge k-halves (kh=1 -> LDS scratch; kh=0 adds and stores) ----
    __syncthreads();
    float* scratch = (float*)lds;   // 2 x 64 x 64 f32 = 32 KB (overlays sWT)
    if (kh == 1) {
        #pragma unroll
        for (int ai = 0; ai < 4; ++ai)
            #pragma unroll
            for (int bj = 0; bj < 4; ++bj)
                #pragma unroll
                for (int r = 0; r < 4; ++r) {
                    const int nloc = ai*16 + (lane >> 4)*4 + r;
                    const int c    = bj*16 + (lane & 15);
                    scratch[wn*4096 + nloc*64 + c] = acc[ai][bj][r];
                }
    }
    __syncthreads();
    if (kh == 0) {
        float* op = opart + (((size_t)chunk*B_ + b)*NN + n0 + wn*64)*CC;
        #pragma unroll
        for (int ai = 0; ai < 4; ++ai)
            #pragma unroll
            for (int bj = 0; bj < 4; ++bj)
                #pragma unroll
                for (int r = 0; r < 4; ++r) {
                    const int nloc = ai*16 + (lane >> 4)*4 + r;
                    const int c    = bj*16 + (lane & 15);
                    op[(size_t)nloc*CC + c] = acc[ai][bj][r] + scratch[wn*4096 + nloc*64 + c];
                }
    }
}

// ---------------------------------------------------------------------------
// Kernel 4: epilogue — y = gamma * sum_chunks(opart) + x (with layout permute)
// ---------------------------------------------------------------------------
__global__ __launch_bounds__(256) void epi_kernel(
    const float* __restrict__ x, const float* __restrict__ opart,
    const float* __restrict__ gamma_p, float* __restrict__ y, int nchunks)
{
    const int idx = blockIdx.x * 256 + threadIdx.x;   // float4 index
    const float gm = gamma_p[0];
    const int c4 = idx & 15;
    const int n  = (idx >> 4) & (NN - 1);
    const int b  = idx >> 16;
    float4 o; o.x = 0.f; o.y = 0.f; o.z = 0.f; o.w = 0.f;
    for (int ch = 0; ch < nchunks; ++ch) {
        const float4 v = ((const float4*)opart)[((size_t)(ch*B_ + b)*NN + n)*16 + c4];
        o.x += v.x; o.y += v.y; o.z += v.z; o.w += v.w;
    }
    const int h = n & 63, w = n >> 6;
    const size_t xi = ((size_t)((b*HH + h)*WW + w)*CC >> 2) + c4;
    const float4 xv = ((const float4*)x)[xi];
    float4 r;
    r.x = fmaf(gm, o.x, xv.x);
    r.y = fmaf(gm, o.y, xv.y);
    r.z = fmaf(gm, o.z, xv.z);
    r.w = fmaf(gm, o.w, xv.w);
    ((float4*)y)[xi] = r;
}

// ---------------------------------------------------------------------------
extern "C" void kernel_launch(void* const* d_in, const int* in_sizes, int n_in,
                              void* d_out, int out_size, void* d_ws, size_t ws_size,
                              hipStream_t stream)
{
    const float* x     = (const float*)d_in[0];
    const float* Wf    = (const float*)d_in[1];
    const float* bf    = (const float*)d_in[2];
    const float* Wg    = (const float*)d_in[3];
    const float* bg    = (const float*)d_in[4];
    const float* Wh    = (const float*)d_in[5];
    const float* bh    = (const float*)d_in[6];
    const float* gamma = (const float*)d_in[7];
    float* out = (float*)d_out;

    float* f_buf  = (float*)d_ws;                          // B*N*8
    float* g2_buf = f_buf  + (size_t)BN*C8_;               // B*N*8
    float* h_buf  = g2_buf + (size_t)BN*C8_;               // B*C*N (c-major)
    float* L2_buf = h_buf  + (size_t)BN*CC;                // B*N
    float* opart  = L2_buf + (size_t)BN;                   // ksplit*B*N*C
    // pm/pz partials alias opart (consumed by combine before pass2 writes it)
    float* pm_buf = opart;                                 // NS*BN
    float* pz_buf = opart + (size_t)NS*BN;                 // NS*BN

    const size_t fixed = (size_t)(BN*C8_*2 + BN*CC + BN);
    int ksplit = 1;
    if      (ws_size >= (fixed + (size_t)8*BN*CC) * 4) ksplit = 8;
    else if (ws_size >= (fixed + (size_t)4*BN*CC) * 4) ksplit = 4;
    else if (ws_size >= (fixed + (size_t)2*BN*CC) * 4) ksplit = 2;

    prep_kernel<<<BN/256, 256, 0, stream>>>(x, Wf, bf, Wg, bg, Wh, bh,
                                            f_buf, g2_buf, h_buf);
    pass1_kernel<<<NS*B_*64, 512, 0, stream>>>(f_buf, g2_buf, pm_buf, pz_buf);
    lse_combine_kernel<<<BN/256, 256, 0, stream>>>(pm_buf, pz_buf, L2_buf);
    pass2_kernel<<<128*ksplit, 256, 0, stream>>>(f_buf, g2_buf, h_buf, L2_buf,
                                                 opart, ksplit);
    epi_kernel<<<(BN*CC/4)/256, 256, 0, stream>>>(x, opart, gamma, out, ksplit);
}

// Round 8
// 180.323 us; speedup vs baseline: 1.9760x; 1.1501x over previous
//
#include <hip/hip_runtime.h>
#include <math.h>

#define B_  4
#define HH  64
#define WW  64
#define CC  64
#define C8_ 8
#define NN  4096
#define BN  (B_*NN)
#define NS  4
#define LOG2E 1.44269504088896340736f

typedef _Float16 half8 __attribute__((ext_vector_type(8)));
typedef float f32x4 __attribute__((ext_vector_type(4)));

// XOR swizzle for 128B-stride f16 rows: spread 16B slots by row&7.
#define SWZ(row, kbyte) ((((row) << 7) + (kbyte)) ^ (((row) & 7) << 4))

// ---------------------------------------------------------------------------
// Kernel 0: zero the fmax atomic buffer (ws is poisoned 0xAA each launch)
// ---------------------------------------------------------------------------
__global__ void zero_fmax_kernel(unsigned* __restrict__ fmax_u) {
    if (threadIdx.x < B_*C8_) fmax_u[threadIdx.x] = 0u;
}

// ---------------------------------------------------------------------------
// Kernel 1: prep — 32 pixels/block, 8 threads/pixel (dg = channel-octet).
// f=relu(Wf^T x) [b][n][8]; g2=relu(Wg^T x)*log2e [b][n][8]; h c-major [b][c][n].
// Also: per-channel f-max block-reduce -> global atomicMax (for pass1 bound).
// ---------------------------------------------------------------------------
#define XSTR 66   // sX row stride (floats)
__global__ __launch_bounds__(256) void prep_kernel(
    const float* __restrict__ x,  const float* __restrict__ Wf, const float* __restrict__ bf,
    const float* __restrict__ Wg, const float* __restrict__ bg, const float* __restrict__ Wh,
    const float* __restrict__ bh, float* __restrict__ f_out, float* __restrict__ g2_out,
    float* __restrict__ h_out, unsigned* __restrict__ fmax_u)
{
    __shared__ float sX[32*XSTR];   // 8.4 KB
    __shared__ float sWh[CC*CC];    // 16 KB
    __shared__ float sWf[CC*C8_];   // 2 KB
    __shared__ float sWg[CC*C8_];   // 2 KB
    const int t  = threadIdx.x;
    const int px = t & 31;
    const int dg = t >> 5;          // 0..7 -> h channels dg*8..+7

    for (int i = t; i < CC*CC/4; i += 256) ((float4*)sWh)[i] = ((const float4*)Wh)[i];
    if (t < 128) {
        ((float4*)sWf)[t] = ((const float4*)Wf)[t];
        ((float4*)sWg)[t] = ((const float4*)Wg)[t];
    }

    const int p0 = blockIdx.x * 32;
    const int b  = p0 >> 12;
    const int n0 = p0 & (NN - 1);
    const int h0 = n0 & 63, w = n0 >> 6;

    // stage x: 32 px x 64 c; thread reads px=t>>3, c-range (t&7)*8
    {
        const int spx = t >> 3, cq = t & 7;
        const float* xr = x + (((size_t)(b*HH + h0 + spx)*WW + w) * CC) + cq*8;
        float4 v0 = ((const float4*)xr)[0], v1 = ((const float4*)xr)[1];
        float* dst = sX + spx*XSTR + cq*8;
        dst[0]=v0.x; dst[1]=v0.y; dst[2]=v0.z; dst[3]=v0.w;
        dst[4]=v1.x; dst[5]=v1.y; dst[6]=v1.z; dst[7]=v1.w;
    }
    __syncthreads();

    const bool do_fg = dg < 2;
    const float* sWfg = (dg == 0) ? sWf : sWg;
    const float* bfg  = (dg == 0) ? bf  : bg;

    float ha[8], fa[8];
    #pragma unroll
    for (int j = 0; j < 8; ++j) {
        ha[j] = bh[dg*8 + j];
        fa[j] = do_fg ? bfg[j] : 0.f;
    }

    const float* xrow = sX + px*XSTR;
    #pragma unroll 4
    for (int c = 0; c < CC; ++c) {
        const float xc = xrow[c];
        const float4 w0 = ((const float4*)sWh)[c*16 + dg*2];
        const float4 w1 = ((const float4*)sWh)[c*16 + dg*2 + 1];
        ha[0] = fmaf(w0.x, xc, ha[0]); ha[1] = fmaf(w0.y, xc, ha[1]);
        ha[2] = fmaf(w0.z, xc, ha[2]); ha[3] = fmaf(w0.w, xc, ha[3]);
        ha[4] = fmaf(w1.x, xc, ha[4]); ha[5] = fmaf(w1.y, xc, ha[5]);
        ha[6] = fmaf(w1.z, xc, ha[6]); ha[7] = fmaf(w1.w, xc, ha[7]);
        if (do_fg) {
            const float4 f0 = ((const float4*)sWfg)[c*2];
            const float4 f1 = ((const float4*)sWfg)[c*2 + 1];
            fa[0] = fmaf(f0.x, xc, fa[0]); fa[1] = fmaf(f0.y, xc, fa[1]);
            fa[2] = fmaf(f0.z, xc, fa[2]); fa[3] = fmaf(f0.w, xc, fa[3]);
            fa[4] = fmaf(f1.x, xc, fa[4]); fa[5] = fmaf(f1.y, xc, fa[5]);
            fa[6] = fmaf(f1.z, xc, fa[6]); fa[7] = fmaf(f1.w, xc, fa[7]);
        }
    }

    const int p = p0 + px, n = n0 + px;
    // h stores (c-major, coalesced over px)
    #pragma unroll
    for (int j = 0; j < 8; ++j)
        h_out[((size_t)(b*CC + dg*8 + j))*NN + n] = fmaxf(ha[j], 0.f);

    float fo[8];
    #pragma unroll
    for (int j = 0; j < 8; ++j) fo[j] = fmaxf(fa[j], 0.f);
    if (dg == 0) {
        float4 a, c4;
        a.x=fo[0]; a.y=fo[1]; a.z=fo[2]; a.w=fo[3];
        c4.x=fo[4]; c4.y=fo[5]; c4.z=fo[6]; c4.w=fo[7];
        ((float4*)(f_out + (size_t)p*C8_))[0] = a;
        ((float4*)(f_out + (size_t)p*C8_))[1] = c4;
    } else if (dg == 1) {
        float4 a, c4;
        a.x=fo[0]*LOG2E; a.y=fo[1]*LOG2E; a.z=fo[2]*LOG2E; a.w=fo[3]*LOG2E;
        c4.x=fo[4]*LOG2E; c4.y=fo[5]*LOG2E; c4.z=fo[6]*LOG2E; c4.w=fo[7]*LOG2E;
        ((float4*)(g2_out + (size_t)p*C8_))[0] = a;
        ((float4*)(g2_out + (size_t)p*C8_))[1] = c4;
    }

    // f-max reduction for pass1's bound
    __syncthreads();
    if (dg == 0) {
        #pragma unroll
        for (int j = 0; j < 8; ++j) sX[px*8 + j] = fo[j];
    }
    __syncthreads();
    if (t < 8) {
        float mx = sX[t];
        for (int q = 1; q < 32; ++q) mx = fmaxf(mx, sX[q*8 + t]);
        atomicMax(&fmax_u[b*C8_ + t], __float_as_uint(mx));
    }
}

// ---------------------------------------------------------------------------
// Kernel 2: pass1 — branchless partial sum-of-exp2 with per-row upper bound:
// bound_k = sum_j g2[k][j]*fmax[j] >= s[k,n] (all factors >= 0, so s>=0 and
// gap <= bound ~ 40 << 126: no underflow of the max term).
// z = sum_n exp2(s - bound). Block: 64 k-rows x 1024 n (NS=4 n-splits).
// ---------------------------------------------------------------------------
__global__ __launch_bounds__(512) void pass1_kernel(
    const float* __restrict__ f_in, const float* __restrict__ g2_in,
    const float* __restrict__ fmax_f, float* __restrict__ pz_out,
    float* __restrict__ bound_out)
{
    __shared__ float sF[128*C8_];
    __shared__ float pzs[8][64];
    const int t  = threadIdx.x;
    const int bi = blockIdx.x;
    const int ktile = bi & 63;
    const int b  = (bi >> 6) & 3;
    const int ns = bi >> 8;
    const int k0 = ktile << 6;
    const int kk = t & 63;
    const int q  = t >> 6;
    const int k  = k0 + kk;

    const float4* gp = (const float4*)(g2_in + ((size_t)b*NN + k)*C8_);
    const float4 g0 = gp[0], g1 = gp[1];
    const float4* fm4 = (const float4*)(fmax_f + b*C8_);
    const float4 m0 = fm4[0], m1 = fm4[1];
    const float bound = g0.x*m0.x + g0.y*m0.y + g0.z*m0.z + g0.w*m0.w
                      + g1.x*m1.x + g1.y*m1.y + g1.z*m1.z + g1.w*m1.w;

    const float4* fb = ((const float4*)f_in) + (size_t)b*8192 + ns*2048;

    float z = 0.f;
    for (int T = 0; T < 8; ++T) {
        __syncthreads();
        if (t < 256) ((float4*)sF)[t] = fb[T*256 + t];
        __syncthreads();
        const float4* sF4 = (const float4*)sF;
        #pragma unroll 8
        for (int i = 0; i < 16; ++i) {
            const int nl = q*16 + i;
            const float4 f0 = sF4[nl*2], f1 = sF4[nl*2 + 1];
            float s = g0.x*f0.x + g0.y*f0.y + g0.z*f0.z + g0.w*f0.w
                    + g1.x*f1.x + g1.y*f1.y + g1.z*f1.z + g1.w*f1.w;
            z += exp2f(s - bound);
        }
    }
    pzs[q][kk] = z;
    __syncthreads();
    if (t < 64) {
        float Z = pzs[0][t];
        #pragma unroll
        for (int qq = 1; qq < 8; ++qq) Z += pzs[qq][t];
        pz_out[(size_t)ns*BN + b*NN + k0 + t] = Z;
        if (ns == 0) bound_out[(size_t)b*NN + k0 + t] = bound;  // q==0 -> own bound
    }
}

// ---------------------------------------------------------------------------
// Kernel 2b: combine NS partials -> L2[b,k] = bound + log2(sum Z)
// ---------------------------------------------------------------------------
__global__ __launch_bounds__(256) void lse_combine_kernel(
    const float* __restrict__ pz, const float* __restrict__ bound_in,
    float* __restrict__ L2_out)
{
    const int r = blockIdx.x * 256 + threadIdx.x;   // < BN
    float Z = 0.f;
    #pragma unroll
    for (int ns = 0; ns < NS; ++ns) Z += pz[(size_t)ns*BN + r];
    L2_out[r] = bound_in[r] + log2f(fmaxf(Z, 1e-37f));
}

// ---------------------------------------------------------------------------
// Kernel 3: pass2 — o[n][c] = sum_k w[k,n]*h[k,c], w = exp2(g2_k.f_n - L2[k]).
// s-dot ALSO on MFMA via packed-K=32 accurate product:
//   A row(g): [g_hi|g_hi|g_lo|0], B col(f): [f_hi|f_lo|f_hi|0]
//   => dot = gh*fh + gh*fl + gl*fh  (error ~2^-22) in ONE 16x16x32 MFMA.
// Block: 256 thr, 128n x 64c tile, ktile=64. Waves: s-phase = k-quarter;
// o-phase = n-quarter (32n x 64c, K=64, hi/lo 3-term = 48 MFMA).
// ---------------------------------------------------------------------------
#define P2_SWH 0        // 16 KB  w_hi [128][64] f16, SWZ
#define P2_SWL 16384    // 16 KB  w_lo
#define P2_SHH 32768    //  8 KB  h_hi [64][64] f16, SWZ
#define P2_SHL 40960    //  8 KB  h_lo
#define P2_SFP 49152    // 10 KB  f packed [128][80B]
#define P2_SGP 59392    //  5 KB  g packed [64][80B]
#define P2_SL  64512    // 256 B  L2 tile
#define P2_LDS 64768

__global__ __launch_bounds__(256, 2) void pass2_kernel(
    const float* __restrict__ f_in, const float* __restrict__ g2_in,
    const float* __restrict__ h_in, const float* __restrict__ L2_in,
    float* __restrict__ opart, int ksplit)
{
    __shared__ __align__(16) unsigned char lds[P2_LDS];

    const int t     = threadIdx.x;
    const int bi    = blockIdx.x;
    const int nt    = bi & 31;
    const int b     = (bi >> 5) & 3;
    const int chunk = bi >> 7;
    const int n0    = nt << 7;
    const int kchunk = NN / ksplit;
    const int kbase0 = chunk * kchunk;
    const int ktiles = kchunk >> 6;

    const int lane = t & 63, wid = t >> 6;
    const int lg = lane >> 4, l15 = lane & 15;
    const uint4 zq = {0u, 0u, 0u, 0u};

    // ---- stage f packed (once): row n, [f_hi | f_lo | f_hi | 0] ----
    if (t < 128) {
        const float4* fp4 = (const float4*)(f_in + ((size_t)b*NN + n0 + t)*C8_);
        const float4 a = fp4[0], c4 = fp4[1];
        float v[8] = {a.x,a.y,a.z,a.w,c4.x,c4.y,c4.z,c4.w};
        union { _Float16 h[8]; uint4 u; } qh, ql;
        #pragma unroll
        for (int j = 0; j < 8; ++j) {
            _Float16 hi = (_Float16)v[j];
            qh.h[j] = hi; ql.h[j] = (_Float16)(v[j] - (float)hi);
        }
        unsigned char* base = lds + P2_SFP + t*80;
        *(uint4*)(base)      = qh.u;
        *(uint4*)(base + 16) = ql.u;
        *(uint4*)(base + 32) = qh.u;
        *(uint4*)(base + 48) = zq;
    }
    __syncthreads();

    // f B-fragments are ktile-invariant: cache in registers
    half8 fB[8];
    #pragma unroll
    for (int ntl = 0; ntl < 8; ++ntl)
        fB[ntl] = *(const half8*)(lds + P2_SFP + (ntl*16 + l15)*80 + lg*16);

    f32x4 oacc[2][4] = {};   // [at][ct]

    for (int kt = 0; kt < ktiles; ++kt) {
        const int kb = kbase0 + (kt << 6);
        __syncthreads();
        // ---- stage g packed, L2, h hi/lo ----
        if (t < 128) {
            const int k = t >> 1, hf = t & 1;
            const float4* gp4 = (const float4*)(g2_in + ((size_t)b*NN + kb + k)*C8_);
            const float4 a = gp4[0], c4 = gp4[1];
            float v[8] = {a.x,a.y,a.z,a.w,c4.x,c4.y,c4.z,c4.w};
            union { _Float16 h[8]; uint4 u; } qh, ql;
            #pragma unroll
            for (int j = 0; j < 8; ++j) {
                _Float16 hi = (_Float16)v[j];
                qh.h[j] = hi; ql.h[j] = (_Float16)(v[j] - (float)hi);
            }
            unsigned char* base = lds + P2_SGP + k*80;
            if (hf == 0) { *(uint4*)(base) = qh.u; *(uint4*)(base + 16) = qh.u; }
            else         { *(uint4*)(base + 32) = ql.u; *(uint4*)(base + 48) = zq; }
        }
        if (t < 16) ((float4*)(lds + P2_SL))[t] =
            ((const float4*)(L2_in + (size_t)b*NN + kb))[t];
        {
            const int c = t >> 2, kq4 = t & 3;
            const float4* hp4 = (const float4*)(h_in + ((size_t)(b*CC + c))*NN + kb + kq4*16);
            float v[16];
            #pragma unroll
            for (int j = 0; j < 4; ++j) {
                float4 w4 = hp4[j];
                v[j*4+0]=w4.x; v[j*4+1]=w4.y; v[j*4+2]=w4.z; v[j*4+3]=w4.w;
            }
            #pragma unroll
            for (int hseg = 0; hseg < 2; ++hseg) {
                union { _Float16 h[8]; uint4 u; } qh, ql;
                #pragma unroll
                for (int j = 0; j < 8; ++j) {
                    float vv = v[hseg*8 + j];
                    _Float16 hi = (_Float16)vv;
                    qh.h[j] = hi; ql.h[j] = (_Float16)(vv - (float)hi);
                }
                const int kbyte = kq4*32 + hseg*16;
                *(uint4*)(lds + P2_SHH + SWZ(c, kbyte)) = qh.u;
                *(uint4*)(lds + P2_SHL + SWZ(c, kbyte)) = ql.u;
            }
        }
        __syncthreads();

        // ---- s-GEMM: wave = k-quarter (16 k rows), 8 n-tiles ----
        {
            const half8 Ag = *(const half8*)(lds + P2_SGP + (wid*16 + l15)*80 + lg*16);
            const float4 L2v = *(const float4*)(lds + P2_SL + wid*64 + lg*16);
            f32x4 sacc[8] = {};
            #pragma unroll
            for (int ntl = 0; ntl < 8; ++ntl)
                sacc[ntl] = __builtin_amdgcn_mfma_f32_16x16x32_f16(Ag, fB[ntl], sacc[ntl], 0, 0, 0);
            // w = exp2(s - L2), split hi/lo, write sW[n][k]
            #pragma unroll
            for (int ntl = 0; ntl < 8; ++ntl) {
                union { _Float16 h[4]; uint2 u; } wh, wl;
                #pragma unroll
                for (int r = 0; r < 4; ++r) {
                    float wv = exp2f(sacc[ntl][r] - L2v[r]);
                    _Float16 hi = (_Float16)wv;
                    wh.h[r] = hi; wl.h[r] = (_Float16)(wv - (float)hi);
                }
                const int n = ntl*16 + l15;
                const int kbyte = wid*32 + lg*8;
                *(uint2*)(lds + P2_SWH + SWZ(n, kbyte)) = wh.u;
                *(uint2*)(lds + P2_SWL + SWZ(n, kbyte)) = wl.u;
            }
        }
        __syncthreads();

        // ---- o-GEMM: wave = n-quarter (32 n), 64 c, K=64 (2 slices), hi/lo 3-term
        #pragma unroll
        for (int ks = 0; ks < 2; ++ks) {
            const int kbyteg = ks*64 + lg*16;
            half8 Ah[2], Al[2];
            #pragma unroll
            for (int at = 0; at < 2; ++at) {
                const int n = wid*32 + at*16 + l15;
                Ah[at] = *(const half8*)(lds + P2_SWH + SWZ(n, kbyteg));
                Al[at] = *(const half8*)(lds + P2_SWL + SWZ(n, kbyteg));
            }
            #pragma unroll
            for (int ct = 0; ct < 4; ++ct) {
                const int c = ct*16 + l15;
                const half8 Bh = *(const half8*)(lds + P2_SHH + SWZ(c, kbyteg));
                const half8 Bl = *(const half8*)(lds + P2_SHL + SWZ(c, kbyteg));
                #pragma unroll
                for (int at = 0; at < 2; ++at) {
                    oacc[at][ct] = __builtin_amdgcn_mfma_f32_16x16x32_f16(Ah[at], Bh, oacc[at][ct], 0, 0, 0);
                    oacc[at][ct] = __builtin_amdgcn_mfma_f32_16x16x32_f16(Ah[at], Bl, oacc[at][ct], 0, 0, 0);
                    oacc[at][ct] = __builtin_amdgcn_mfma_f32_16x16x32_f16(Al[at], Bh, oacc[at][ct], 0, 0, 0);
                }
            }
        }
    }

    // ---- store: D layout col=l15 (c), row=lg*4+r (n within 16-tile) ----
    float* op = opart + (((size_t)chunk*B_ + b)*NN + n0 + wid*32)*CC;
    #pragma unroll
    for (int at = 0; at < 2; ++at)
        #pragma unroll
        for (int ct = 0; ct < 4; ++ct)
            #pragma unroll
            for (int r = 0; r < 4; ++r)
                op[(size_t)(at*16 + lg*4 + r)*CC + ct*16 + l15] = oacc[at][ct][r];
}

// ---------------------------------------------------------------------------
// Kernel 4: epilogue — y = gamma * sum_chunks(opart) + x (layout permute)
// ---------------------------------------------------------------------------
__global__ __launch_bounds__(256) void epi_kernel(
    const float* __restrict__ x, const float* __restrict__ opart,
    const float* __restrict__ gamma_p, float* __restrict__ y, int nchunks)
{
    const int idx = blockIdx.x * 256 + threadIdx.x;   // float4 index
    const float gm = gamma_p[0];
    const int c4 = idx & 15;
    const int n  = (idx >> 4) & (NN - 1);
    const int b  = idx >> 16;
    float4 o; o.x = 0.f; o.y = 0.f; o.z = 0.f; o.w = 0.f;
    for (int ch = 0; ch < nchunks; ++ch) {
        const float4 v = ((const float4*)opart)[((size_t)(ch*B_ + b)*NN + n)*16 + c4];
        o.x += v.x; o.y += v.y; o.z += v.z; o.w += v.w;
    }
    const int h = n & 63, w = n >> 6;
    const size_t xi = ((size_t)((b*HH + h)*WW + w)*CC >> 2) + c4;
    const float4 xv = ((const float4*)x)[xi];
    float4 r;
    r.x = fmaf(gm, o.x, xv.x);
    r.y = fmaf(gm, o.y, xv.y);
    r.z = fmaf(gm, o.z, xv.z);
    r.w = fmaf(gm, o.w, xv.w);
    ((float4*)y)[xi] = r;
}

// ---------------------------------------------------------------------------
extern "C" void kernel_launch(void* const* d_in, const int* in_sizes, int n_in,
                              void* d_out, int out_size, void* d_ws, size_t ws_size,
                              hipStream_t stream)
{
    const float* x     = (const float*)d_in[0];
    const float* Wf    = (const float*)d_in[1];
    const float* bf    = (const float*)d_in[2];
    const float* Wg    = (const float*)d_in[3];
    const float* bg    = (const float*)d_in[4];
    const float* Wh    = (const float*)d_in[5];
    const float* bh    = (const float*)d_in[6];
    const float* gamma = (const float*)d_in[7];
    float* out = (float*)d_out;

    float* f_buf   = (float*)d_ws;                         // BN*8
    float* g2_buf  = f_buf    + (size_t)BN*C8_;            // BN*8
    float* h_buf   = g2_buf   + (size_t)BN*C8_;            // BN*64 (c-major)
    float* L2_buf  = h_buf    + (size_t)BN*CC;             // BN
    float* pz_buf  = L2_buf   + (size_t)BN;                // NS*BN
    float* bnd_buf = pz_buf   + (size_t)NS*BN;             // BN
    float* fmax_b  = bnd_buf  + (size_t)BN;                // 32
    float* opart   = fmax_b   + 32;                        // ksplit*BN*64

    const size_t fixedf = (size_t)BN*(C8_*2 + CC + 1 + NS + 1) + 32;
    int ksplit = 1;
    if      (ws_size >= (fixedf + (size_t)4*BN*CC) * 4) ksplit = 4;
    else if (ws_size >= (fixedf + (size_t)2*BN*CC) * 4) ksplit = 2;

    zero_fmax_kernel<<<1, 64, 0, stream>>>((unsigned*)fmax_b);
    prep_kernel<<<BN/32, 256, 0, stream>>>(x, Wf, bf, Wg, bg, Wh, bh,
                                           f_buf, g2_buf, h_buf, (unsigned*)fmax_b);
    pass1_kernel<<<NS*B_*64, 512, 0, stream>>>(f_buf, g2_buf, fmax_b, pz_buf, bnd_buf);
    lse_combine_kernel<<<BN/256, 256, 0, stream>>>(pz_buf, bnd_buf, L2_buf);
    pass2_kernel<<<128*ksplit, 256, 0, stream>>>(f_buf, g2_buf, h_buf, L2_buf,
                                                 opart, ksplit);
    epi_kernel<<<(BN*CC/4)/256, 256, 0, stream>>>(x, opart, gamma, out, ksplit);
}